// Round 15
// baseline (1405.093 us; speedup 1.0000x reference)
//
#include <hip/hip_runtime.h>
#include <stdint.h>

// ---------------------------------------------------------------------------
// Dwtpool fused pipeline, MI355X gfx950.  Round 15 (= r11 with 16-wave conv):
//  - k_conv_gemm256: 256x256 tile, 1024 threads (16 waves, 4 waves/SIMD),
//    wave-tile 64x64 (acc[4][4]), BK=32, 4 rotating 32KB LDS buffers,
//    distance-2 staging (1 A + 1 B gload/thread/tile, counted vmcnt(2)),
//    r5-verified paired-row-line LDS rotation (8-line periodic => offsets
//    content-identical), 16x16x32 MFMA, same two-phase barrier schedule.
//    Theory: 4 waves/SIMD TLP hides the exposed ds_read/issue latency that
//    capped all 2-wave/SIMD schedules at ~47% MfmaUtil.
//  - everything else identical to r11/r14 (algebraic folds + parallel tail).
// ---------------------------------------------------------------------------

typedef __attribute__((ext_vector_type(8))) short bf16x8;
typedef __attribute__((ext_vector_type(4))) float f32x4;

#define EPS_ 1e-5f

#define GLOAD16(gp, lp)                                                        \
  __builtin_amdgcn_global_load_lds(                                            \
      (const __attribute__((address_space(1))) void*)(gp),                     \
      (__attribute__((address_space(3))) void*)(lp), 16, 0, 0)

__device__ __forceinline__ float bf2f(unsigned short u) {
  union { unsigned int u; float f; } c; c.u = ((unsigned int)u) << 16; return c.f;
}
__device__ __forceinline__ unsigned short f2bf(float f) {
  union { float f; unsigned int u; } c; c.f = f;
  return (unsigned short)((c.u + 0x7fffu + ((c.u >> 16) & 1u)) >> 16);
}
__device__ __forceinline__ void unpack8(uint4 v, float* f) {
  f[0]=bf2f((unsigned short)(v.x&0xffffu)); f[1]=bf2f((unsigned short)(v.x>>16));
  f[2]=bf2f((unsigned short)(v.y&0xffffu)); f[3]=bf2f((unsigned short)(v.y>>16));
  f[4]=bf2f((unsigned short)(v.z&0xffffu)); f[5]=bf2f((unsigned short)(v.z>>16));
  f[6]=bf2f((unsigned short)(v.w&0xffffu)); f[7]=bf2f((unsigned short)(v.w>>16));
}
__device__ __forceinline__ uint4 pack8(const float* f) {
  uint4 v;
  v.x = (unsigned)f2bf(f[0]) | ((unsigned)f2bf(f[1])<<16);
  v.y = (unsigned)f2bf(f[2]) | ((unsigned)f2bf(f[3])<<16);
  v.z = (unsigned)f2bf(f[4]) | ((unsigned)f2bf(f[5])<<16);
  v.w = (unsigned)f2bf(f[6]) | ((unsigned)f2bf(f[7])<<16);
  return v;
}

// --- weight repack: OIHW f32 -> [tap][Opad][I] bf16 (zero rows O..Opad) ----
__global__ void k_repack(const float* __restrict__ src, unsigned short* __restrict__ dst,
                         int O, int Opad, int I, int T) {
  int gid = blockIdx.x * 256 + threadIdx.x;
  if (gid >= Opad * I * T) return;
  int i = gid % I; int r = gid / I; int o = r % Opad; int t = r / Opad;
  dst[gid] = (o < O) ? f2bf(src[((size_t)(o * I + i)) * T + t]) : (unsigned short)0;
}

// --- fold conv1 into big-conv weights: WBIG[t][o][1280] bf16 ---------------
__global__ void k_fold1(const float* __restrict__ catw, const float* __restrict__ w1,
                        unsigned short* __restrict__ dst) {
  int gid = blockIdx.x; int tid = threadIdx.x;
  int iq = gid % 5; int o = (gid / 5) & 255; int t = gid / 1280;
  int i = iq * 256 + tid;
  float s;
  if (i < 256) {
    s = catw[((size_t)o * 1536 + i) * 9 + t];
    const float* cw = catw + ((size_t)o * 1536 + 256) * 9 + t;
    for (int m = 0; m < 256; ++m)
      s += cw[(size_t)m * 9] * w1[m * 256 + i];
  } else {
    s = catw[((size_t)o * 1536 + i + 256) * 9 + t];
  }
  dst[((size_t)t * 256 + o) * 1280 + i] = f2bf(s);
}

// --- zero border ring of a padded NHWC buffer (16 batches) -----------------
__global__ void k_border_zero(unsigned short* __restrict__ buf, int PW, int PB, int C) {
  int IW = PW - 2 * PB;
  int nb = PW * PW - IW * IW;
  int per = C >> 3;
  int gid = blockIdx.x * 256 + threadIdx.x;
  if (gid >= 16 * nb * per) return;
  int cq = gid % per; int r = gid / per; int p = r % nb; int b = r / nb;
  int y, x;
  int top = PB * PW;
  if (p < top) { y = p / PW; x = p - y * PW; }
  else if (p < top + IW * 2 * PB) {
    int q = p - top; y = PB + q / (2 * PB); int rr = q % (2 * PB);
    x = (rr < PB) ? rr : (IW + rr);
  } else { int q = p - top - IW * 2 * PB; y = PB + IW + q / PW; x = q - (q / PW) * PW; }
  uint4 z; z.x = z.y = z.z = z.w = 0u;
  *(uint4*)&buf[(((size_t)b * PW + y) * PW + x) * C + cq * 8] = z;
}

// --- x: NCHW f32 -> NHWC bf16 [16][128][128][256] --------------------------
__global__ void k_transpose_x(const float* __restrict__ x, unsigned short* __restrict__ xh) {
  int by = blockIdx.x; int b = by >> 7; int y = by & 127;
  int tid = threadIdx.x;
  __shared__ unsigned short lds[32 * 129];
  for (int c0 = 0; c0 < 256; c0 += 32) {
    #pragma unroll
    for (int i = 0; i < 16; ++i) {
      int e = i * 256 + tid; int ci = e >> 7, xx = e & 127;
      float v = x[(((size_t)b * 256 + c0 + ci) * 128 + y) * 128 + xx];
      lds[ci * 129 + xx] = f2bf(v);
    }
    __syncthreads();
    #pragma unroll
    for (int i2 = 0; i2 < 2; ++i2) {
      int e = i2 * 256 + tid; int pix = e >> 2, q = e & 3;
      unsigned int w0, w1, w2, w3;
      w0 = (unsigned)lds[(q*8+0)*129 + pix] | ((unsigned)lds[(q*8+1)*129 + pix] << 16);
      w1 = (unsigned)lds[(q*8+2)*129 + pix] | ((unsigned)lds[(q*8+3)*129 + pix] << 16);
      w2 = (unsigned)lds[(q*8+4)*129 + pix] | ((unsigned)lds[(q*8+5)*129 + pix] << 16);
      w3 = (unsigned)lds[(q*8+6)*129 + pix] | ((unsigned)lds[(q*8+7)*129 + pix] << 16);
      uint4 v; v.x = w0; v.y = w1; v.z = w2; v.w = w3;
      *(uint4*)&xh[(((size_t)b * 128 + y) * 128 + pix) * 256 + c0 + q * 8] = v;
    }
    __syncthreads();
  }
}

// --- maxpool 2x2 on xh -> CAT(padded 70x70, 1280ch) channels [1024..1280) --
__global__ void k_maxpool(const unsigned short* __restrict__ xh, unsigned short* __restrict__ cat) {
  int gid = blockIdx.x * 256 + threadIdx.x;        // 16*4096*32
  int cq = gid & 31; int pix = gid >> 5;
  int bb = pix >> 12; int yx = pix & 4095;
  int y = yx >> 6, xx2 = yx & 63;
  size_t base = (((size_t)bb * 128 + 2 * y) * 128 + 2 * xx2) * 256 + cq * 8;
  uint4 v00 = *(const uint4*)(xh + base);
  uint4 v01 = *(const uint4*)(xh + base + 256);
  uint4 v10 = *(const uint4*)(xh + base + 32768);
  uint4 v11 = *(const uint4*)(xh + base + 32768 + 256);
  float a[8], b8[8], c8[8], d8[8], m8[8];
  unpack8(v00, a); unpack8(v01, b8); unpack8(v10, c8); unpack8(v11, d8);
  #pragma unroll
  for (int j = 0; j < 8; ++j) m8[j] = fmaxf(fmaxf(a[j], b8[j]), fmaxf(c8[j], d8[j]));
  *(uint4*)(cat + (((size_t)bb * 4900 + (y + 3) * 70 + (xx2 + 3))) * 1280 + 1024 + cq * 8) = pack8(m8);
}

// --- haar DWT: rbn [16][128][128][64] -> CAT(padded,1280) ch [0..256) ------
__global__ void k_haar(const unsigned short* __restrict__ rbn, unsigned short* __restrict__ cat) {
  int gid = blockIdx.x * 256 + threadIdx.x;        // 16*4096*8
  int cq = gid & 7; int pix = gid >> 3;
  int bb = pix >> 12; int yx = pix & 4095;
  int y = yx >> 6, xx = yx & 63;
  size_t base = (((size_t)bb * 128 + 2 * y) * 128 + 2 * xx) * 64 + cq * 8;
  uint4 va = *(const uint4*)(rbn + base);
  uint4 vb = *(const uint4*)(rbn + base + 64);
  uint4 vc = *(const uint4*)(rbn + base + 8192);
  uint4 vd = *(const uint4*)(rbn + base + 8192 + 64);
  float a[8], b8[8], c8[8], d8[8], o[8];
  unpack8(va, a); unpack8(vb, b8); unpack8(vc, c8); unpack8(vd, d8);
  size_t ob = ((size_t)bb * 4900 + (y + 3) * 70 + (xx + 3)) * 1280 + cq * 8;
  #pragma unroll
  for (int j = 0; j < 8; ++j) o[j] = (a[j] + b8[j] + c8[j] + d8[j]) * 0.5f;
  *(uint4*)(cat + ob + 0)   = pack8(o);
  #pragma unroll
  for (int j = 0; j < 8; ++j) o[j] = (a[j] + b8[j] - c8[j] - d8[j]) * 0.5f;
  *(uint4*)(cat + ob + 64)  = pack8(o);
  #pragma unroll
  for (int j = 0; j < 8; ++j) o[j] = (a[j] - b8[j] + c8[j] - d8[j]) * 0.5f;
  *(uint4*)(cat + ob + 128) = pack8(o);
  #pragma unroll
  for (int j = 0; j < 8; ++j) o[j] = (a[j] - b8[j] - c8[j] + d8[j]) * 0.5f;
  *(uint4*)(cat + ob + 192) = pack8(o);
}

// ===========================================================================
// 256x256 implicit-GEMM conv: 16 waves (4/SIMD), wave-tile 64x64, BK=32,
// 4 rotating 32KB LDS buffers, distance-2 staging, counted vmcnt(2).
// LDS: paired-row 128B lines, chunk rotation by line&7 (r5-verified, pattern
// is 8-line periodic so all offsets remain content-identical).
// ===========================================================================
__global__ __launch_bounds__(1024, 1) void k_conv_gemm256(
    const unsigned short* __restrict__ Wt, const unsigned short* __restrict__ Bf,
    int Cin, int Cstr, int cbase,
    int PW, int PB, int KH, int pad,
    unsigned long long wbstride,
    unsigned short* __restrict__ outb, int OCstr, int ocbase, int OPW, int OPB,
    float* __restrict__ outf, int mode) {
  const int tid = threadIdx.x, lane = tid & 63, w = tid >> 6;   // w 0..15
  const int wm = w >> 2, wn = w & 3;
  const int nidx = (blockIdx.x & 7) * 32 + (blockIdx.x >> 3);
  const int bn = (nidx & 15) * 256;
  const int b = nidx >> 4;
  if (wbstride) Wt += (size_t)b * wbstride;
  extern __shared__ unsigned short S[];   // 4 buffers x 16384 shorts = 128KB

  f32x4 zero4 = {0.f, 0.f, 0.f, 0.f};
  f32x4 acc[4][4];
  #pragma unroll
  for (int i = 0; i < 4; ++i)
    #pragma unroll
    for (int j = 0; j < 4; ++j) acc[i][j] = zero4;

  // ---- staging (paired-row lines): wave w covers rows w*16..w*16+15 of
  //      each half (A rows, B pixels); 1 A instr + 1 B instr per tile ----
  const int lq = lane >> 3, lc = lane & 7;
  const int lg = (lc - lq) & 7;
  const int pr = lg >> 2;
  const int ks = lg & 3;
  const unsigned short* aSt = Wt + (size_t)(w * 16 + 2 * lq + pr) * Cin + ks * 8;
  const size_t bimg = (size_t)b * PW * PW;
  const unsigned short* bSt;
  {
    int p = bn + w * 16 + 2 * lq + pr;
    bSt = Bf + (bimg + (size_t)((p >> 6) + PB) * PW + ((p & 63) + PB)) * Cstr + cbase + ks * 8;
  }
  const int dA = w * 512;                       // shorts within buffer
  const int dB = 8192 + w * 512;

  // ---- fragment read offsets (identical lb to r5; 8-line periodic) ----
  const int r = lane & 15, s4 = lane >> 4;
  const int ck = (((r & 1) * 4 + s4) + ((r >> 1) & 7)) & 7;
  const int lb = (r >> 1) * 64 + ck * 8;
  const int aOff = wm * 2048 + lb;              // + mi*512, mi 0..3
  const int bOff = 8192 + wn * 2048 + lb;       // + ni*512, ni 0..3

  const size_t MC = (size_t)256 * Cin;
  const int NT = (KH * KH * Cin) >> 5;

  // ---- prologue: stage tiles 0,1 into buffers 0,1 ----
  const long long t0B = ((long long)(-pad) * PW + (-pad)) * (long long)Cstr;
  #pragma unroll
  for (int tb = 0; tb < 2; ++tb) {
    unsigned short* Sw = S + tb * 16384;
    GLOAD16(aSt + tb * 32,       Sw + dA);
    GLOAD16(bSt + t0B + tb * 32, Sw + dB);
  }
  asm volatile("s_waitcnt vmcnt(2)" ::: "memory");  // tile 0 landed
  __builtin_amdgcn_s_barrier();
  __builtin_amdgcn_sched_barrier(0);

  int kc2 = 64, ty2 = 0, tx2 = 0;
  for (int t = 0; t < NT; ++t) {
    const unsigned short* Sc = S + (t & 3) * 16384;
    unsigned short* Sn = (unsigned short*)S + ((t + 2) & 3) * 16384;
    const bool hn = (t + 2) < NT;
    long long offA = 0, offB = 0;
    if (hn) {
      offA = (long long)(ty2 * KH + tx2) * MC + kc2;
      offB = ((long long)(ty2 - pad) * PW + (tx2 - pad)) * (long long)Cstr + kc2;
      kc2 += 32;
      if (kc2 == Cin) { kc2 = 0; ++tx2; if (tx2 == KH) { tx2 = 0; ++ty2; } }
    }
    bf16x8 a[2], bb[4];
    // ---- phase 0: frags A(mi0-1)+B(all); stage A of tile t+2 ----
    #pragma unroll
    for (int mi = 0; mi < 2; ++mi) a[mi] = *(const bf16x8*)(Sc + aOff + mi * 512);
    #pragma unroll
    for (int ni = 0; ni < 4; ++ni) bb[ni] = *(const bf16x8*)(Sc + bOff + ni * 512);
    if (hn) GLOAD16(aSt + offA, Sn + dA);
    __builtin_amdgcn_s_setprio(1);
    #pragma unroll
    for (int mi = 0; mi < 2; ++mi)
      #pragma unroll
      for (int ni = 0; ni < 4; ++ni)
        acc[mi][ni] = __builtin_amdgcn_mfma_f32_16x16x32_bf16(a[mi], bb[ni], acc[mi][ni], 0, 0, 0);
    __builtin_amdgcn_s_setprio(0);
    __builtin_amdgcn_s_barrier();
    // ---- phase 1: frags A(mi2-3); stage B of tile t+2 ----
    #pragma unroll
    for (int mi = 0; mi < 2; ++mi) a[mi] = *(const bf16x8*)(Sc + aOff + (mi + 2) * 512);
    if (hn) GLOAD16(bSt + offB, Sn + dB);
    __builtin_amdgcn_s_setprio(1);
    #pragma unroll
    for (int mi = 0; mi < 2; ++mi)
      #pragma unroll
      for (int ni = 0; ni < 4; ++ni)
        acc[mi + 2][ni] = __builtin_amdgcn_mfma_f32_16x16x32_bf16(a[mi], bb[ni], acc[mi + 2][ni], 0, 0, 0);
    __builtin_amdgcn_s_setprio(0);
    // ---- tile boundary: counted wait + barrier ----
    if (t + 1 < NT) {
      if (t + 2 < NT) { asm volatile("s_waitcnt vmcnt(2)" ::: "memory"); }
      else            { asm volatile("s_waitcnt vmcnt(0)" ::: "memory"); }
      __builtin_amdgcn_s_barrier();
      __builtin_amdgcn_sched_barrier(0);
    }
  }

  // ---- epilogue ----
  const size_t bimgO = (size_t)b * OPW * OPW;
  #pragma unroll
  for (int mi = 0; mi < 4; ++mi) {
    const int mf = wm * 64 + mi * 16 + (lane >> 4) * 4;
    #pragma unroll
    for (int ni = 0; ni < 4; ++ni) {
      const int n = bn + wn * 64 + ni * 16 + (lane & 15);
      if (mode == 2) {
        #pragma unroll
        for (int vv = 0; vv < 4; ++vv)
          outf[((size_t)b * 256 + mf + vv) * 4096 + n] = acc[mi][ni][vv];
      } else {
        const int oy = n >> 6, ox = n & 63;
        unsigned short h[4];
        #pragma unroll
        for (int vv = 0; vv < 4; ++vv) h[vv] = f2bf(acc[mi][ni][vv]);
        uint2 st; st.x = (unsigned)h[0] | ((unsigned)h[1] << 16);
        st.y = (unsigned)h[2] | ((unsigned)h[3] << 16);
        *(uint2*)&outb[(bimgO + (size_t)(oy + OPB) * OPW + (ox + OPB)) * OCstr + ocbase + mf] = st;
      }
    }
  }
}

// --- 128^2 implicit-GEMM conv (kept for M=64 reduce conv, mode 1) ----------
__global__ __launch_bounds__(256) void k_conv_gemm(
    const unsigned short* __restrict__ Wt, const unsigned short* __restrict__ Bf,
    int M, int Mpad, int Cin, int Cstr, int cbase,
    int OW, int lgOW, int PW, int PB, int KH, int pad,
    unsigned long long wbstride,
    unsigned short* __restrict__ outb, int OCstr, int ocbase, int OPW, int OPB,
    float* __restrict__ outf, int mode,
    const float* __restrict__ rb, const float* __restrict__ bng, const float* __restrict__ bnb,
    const float* __restrict__ bnm, const float* __restrict__ bnv) {
  const int tid = threadIdx.x, lane = tid & 63, w = tid >> 6;
  const int wm = w >> 1, wn = w & 1;
  const int bm = blockIdx.y * 128, bn = blockIdx.x * 128;
  const int b = blockIdx.z;
  const int Npix = OW * OW;
  if (wbstride) Wt += (size_t)b * wbstride;

  __shared__ __align__(1024) unsigned short sA[128 * 32];
  __shared__ __align__(1024) unsigned short sB[128 * 32];

  f32x4 zero4 = {0.f, 0.f, 0.f, 0.f};
  f32x4 acc[4][4];
  #pragma unroll
  for (int i = 0; i < 4; ++i)
    #pragma unroll
    for (int j = 0; j < 4; ++j) acc[i][j] = zero4;

  const int srow = lane >> 2;
  const int slog = (lane & 3) ^ ((lane >> 3) & 3);
  const int r0 = w * 32;
  const unsigned short* aRow = Wt + ((size_t)(bm + r0 + srow)) * Cin + slog * 8;
  const int n0 = bn + r0 + srow, n1 = n0 + 16;
  const int y0 = n0 >> lgOW, x0 = n0 & (OW - 1);
  const int y1 = n1 >> lgOW, x1 = n1 & (OW - 1);
  const size_t bimg = (size_t)b * PW * PW;
  const unsigned short* bRow0 = Bf + (bimg + (size_t)(y0 + PB) * PW + (x0 + PB)) * Cstr + cbase + slog * 8;
  const unsigned short* bRow1 = Bf + (bimg + (size_t)(y1 + PB) * PW + (x1 + PB)) * Cstr + cbase + slog * 8;
  unsigned short* ldsA0 = &sA[(r0) * 32];
  unsigned short* ldsA1 = &sA[(r0 + 16) * 32];
  unsigned short* ldsB0 = &sB[(r0) * 32];
  unsigned short* ldsB1 = &sB[(r0 + 16) * 32];

  const int rowfrag = lane & 15, hi = lane >> 4;
  const int sl = hi ^ ((rowfrag >> 1) & 3);
  const bf16x8* pA[4]; const bf16x8* pB[4];
  #pragma unroll
  for (int mi = 0; mi < 4; ++mi)
    pA[mi] = (const bf16x8*)&sA[(wm * 64 + mi * 16 + rowfrag) * 32 + sl * 8];
  #pragma unroll
  for (int ni = 0; ni < 4; ++ni)
    pB[ni] = (const bf16x8*)&sB[(wn * 64 + ni * 16 + rowfrag) * 32 + sl * 8];

  const size_t MC = (size_t)Mpad * Cin;
  for (int ty = 0; ty < KH; ++ty) {
    for (int tx = 0; tx < KH; ++tx) {
      const unsigned short* at = aRow + (size_t)(ty * KH + tx) * MC;
      const long long toff = ((long long)(ty - pad) * PW + (tx - pad)) * Cstr;
      const unsigned short* bt0 = bRow0 + toff;
      const unsigned short* bt1 = bRow1 + toff;
      for (int kc = 0; kc < Cin; kc += 32) {
        GLOAD16(at + kc, ldsA0);
        GLOAD16(at + (size_t)16 * Cin + kc, ldsA1);
        GLOAD16(bt0 + kc, ldsB0);
        GLOAD16(bt1 + kc, ldsB1);
        __syncthreads();
        bf16x8 af[4], bfr[4];
        #pragma unroll
        for (int mi = 0; mi < 4; ++mi) af[mi] = *pA[mi];
        #pragma unroll
        for (int ni = 0; ni < 4; ++ni) bfr[ni] = *pB[ni];
        #pragma unroll
        for (int mi = 0; mi < 4; ++mi)
          #pragma unroll
          for (int ni = 0; ni < 4; ++ni)
            acc[mi][ni] = __builtin_amdgcn_mfma_f32_16x16x32_bf16(af[mi], bfr[ni], acc[mi][ni], 0, 0, 0);
        __syncthreads();
      }
    }
  }

  const int mb0 = bm + wm * 64, nb0 = bn + wn * 64;
  const size_t bimgO = (size_t)b * OPW * OPW;
  #pragma unroll
  for (int mi = 0; mi < 4; ++mi) {
    const int mf = mb0 + mi * 16 + (lane >> 4) * 4;
    if (mf >= M) continue;
    #pragma unroll
    for (int ni = 0; ni < 4; ++ni) {
      const int n = nb0 + ni * 16 + (lane & 15);
      if (mode == 2) {
        #pragma unroll
        for (int vv = 0; vv < 4; ++vv)
          outf[((size_t)b * M + mf + vv) * Npix + n] = acc[mi][ni][vv];
      } else {
        const int oy = n >> lgOW, ox = n & (OW - 1);
        unsigned short h[4];
        #pragma unroll
        for (int vv = 0; vv < 4; ++vv) {
          float val = acc[mi][ni][vv];
          if (mode == 1) {
            int m = mf + vv;
            float scl = bng[m] * rsqrtf(bnv[m] + EPS_);
            val = (val + rb[m] - bnm[m]) * scl + bnb[m];
            val = fmaxf(val, 0.f);
          }
          h[vv] = f2bf(val);
        }
        uint2 st; st.x = (unsigned)h[0] | ((unsigned)h[1] << 16);
        st.y = (unsigned)h[2] | ((unsigned)h[3] << 16);
        *(uint2*)&outb[(bimgO + (size_t)(oy + OPB) * OPW + (ox + OPB)) * OCstr + ocbase + mf] = st;
      }
    }
  }
}

// --- content logits: dot(qkv[pix], w) over 256 ch --------------------------
__global__ void k_content_logits(const unsigned short* __restrict__ qkv,
                                 const float* __restrict__ conv_w,
                                 float* __restrict__ logits) {
  int j = blockIdx.x, b = blockIdx.y, tid = threadIdx.x;
  __shared__ float wl[256];
  wl[tid] = conv_w[tid];
  __syncthreads();
  int pl = tid >> 3, kp = tid & 7;
  #pragma unroll
  for (int pass = 0; pass < 4; ++pass) {
    int p = j * 128 + pass * 32 + pl;
    int y = p >> 6, x = p & 63;
    const unsigned short* q = qkv + (((size_t)b * 66 + y + 1) * 66 + (x + 1)) * 256 + kp * 32;
    float s = 0.f;
    #pragma unroll
    for (int i = 0; i < 32; i += 8) {
      uint4 v = *(const uint4*)(q + i);
      float f[8]; unpack8(v, f);
      #pragma unroll
      for (int k = 0; k < 8; ++k) s += f[k] * wl[kp * 32 + i + k];
    }
    s += __shfl_down(s, 4, 8);
    s += __shfl_down(s, 2, 8);
    s += __shfl_down(s, 1, 8);
    if (kp == 0) logits[(size_t)b * 4096 + p] = s;
  }
}

// --- softmax over 4096 per batch (in place) --------------------------------
__global__ void k_softmax4096(float* __restrict__ cont) {
  int b = blockIdx.x, tid = threadIdx.x;
  __shared__ float red[256];
  float sv[16]; float mx = -1e30f;
  #pragma unroll
  for (int j = 0; j < 16; ++j) { sv[j] = cont[(size_t)b * 4096 + j * 256 + tid]; mx = fmaxf(mx, sv[j]); }
  red[tid] = mx; __syncthreads();
  for (int s = 128; s > 0; s >>= 1) { if (tid < s) red[tid] = fmaxf(red[tid], red[tid + s]); __syncthreads(); }
  mx = red[0]; __syncthreads();
  float sum = 0.f;
  #pragma unroll
  for (int j = 0; j < 16; ++j) { sv[j] = expf(sv[j] - mx); sum += sv[j]; }
  red[tid] = sum; __syncthreads();
  for (int s = 128; s > 0; s >>= 1) { if (tid < s) red[tid] += red[tid + s]; __syncthreads(); }
  float inv = 1.f / red[0];
  #pragma unroll
  for (int j = 0; j < 16; ++j) cont[(size_t)b * 4096 + j * 256 + tid] = sv[j] * inv;
}

// --- G correlation, per-row: gpart[b][j][t][i], j = qkv row 0..63 ----------
__global__ void k_corr(const unsigned short* __restrict__ qkv,
                       const float* __restrict__ cont, float* __restrict__ gpart) {
  int j = blockIdx.x, b = blockIdx.y, i = threadIdx.x;   // j: row 0..63
  __shared__ float cl[192];                              // content rows j-1,j,j+1
  if (i < 192) {
    int gy = j - 1 + (i >> 6);
    cl[i] = (gy >= 0 && gy < 64) ? cont[(size_t)b * 4096 + gy * 64 + (i & 63)] : 0.f;
  }
  __syncthreads();
  float g[9] = {0.f, 0.f, 0.f, 0.f, 0.f, 0.f, 0.f, 0.f, 0.f};
  const unsigned short* qrow = qkv + (((size_t)b * 66 + j + 1) * 66 + 1) * 256 + i;
  for (int x = 0; x < 64; ++x) {
    float qv = bf2f(qrow[(size_t)x * 256]);
    #pragma unroll
    for (int ky = 0; ky < 3; ++ky) {
      const int ly = 2 - ky;                             // content row j-ky+1
      #pragma unroll
      for (int kx = 0; kx < 3; ++kx) {
        int nx = x - kx + 1;
        if ((unsigned)nx < 64u) g[ky * 3 + kx] += qv * cl[ly * 64 + nx];
      }
    }
  }
  size_t base = ((size_t)b * 64 + j) * 2304 + i;
  #pragma unroll
  for (int t = 0; t < 9; ++t) gpart[base + t * 256] = g[t];
}

// --- reduce gpart over 64 rows: gred[b][t*256+i] ---------------------------
__global__ void k_gred(const float* __restrict__ gpart, float* __restrict__ gred) {
  int gid = blockIdx.x * 256 + threadIdx.x;              // 16*2304
  if (gid >= 16 * 2304) return;
  int b = gid / 2304, e = gid - b * 2304;
  float s = 0.f;
  const float* p = gpart + (size_t)b * 64 * 2304 + e;
  for (int j = 0; j < 64; ++j) s += p[(size_t)j * 2304];
  gred[gid] = s;
}

// --- pooled[b][c] = sum_{i,t} wc[c][i][t] * G[t][i]  (256 blocks) ----------
__global__ void k_pooled_g(const float* __restrict__ gred,
                           const float* __restrict__ wc, float* __restrict__ pooled) {
  int cg = blockIdx.x, b = blockIdx.y;                   // cg 0..15
  int tid = threadIdx.x;
  int cl_ = tid >> 4, part = tid & 15;                   // 16 ch x 16 parts
  __shared__ float Gs[2304];
  __shared__ float red[256];
  for (int e = tid; e < 2304; e += 256) {
    int i = e / 9, t = e - i * 9;
    Gs[e] = gred[(size_t)b * 2304 + t * 256 + i];        // Gs[i*9+t] = G[t][i]
  }
  __syncthreads();
  int c = cg * 16 + cl_;
  const float* w = wc + (size_t)c * 2304 + part;
  float acc = 0.f;
  #pragma unroll 4
  for (int q = 0; q < 144; ++q) acc += w[q * 16] * Gs[part + q * 16];
  red[tid] = acc;
  __syncthreads();
  if (part == 0) {
    float s = 0.f;
    #pragma unroll
    for (int q = 0; q < 16; ++q) s += red[cl_ * 16 + q];
    pooled[b * 256 + c] = s;
  }
}

// --- ct1 -> LN -> relu -> ct2 ----------------------------------------------
__global__ void k_ct(const float* __restrict__ pooled,
                     const float* __restrict__ ct1w, const float* __restrict__ ct1b,
                     const float* __restrict__ lng, const float* __restrict__ lnb,
                     const float* __restrict__ ct2w, const float* __restrict__ ct2b,
                     float* __restrict__ cw) {
  int b = blockIdx.x, tid = threadIdx.x;
  __shared__ float tt[32];
  __shared__ float stats[2];
  if (tid < 32) {
    float s = 0.f;
    const float* w = ct1w + tid * 256;
    const float* p = pooled + b * 256;
    for (int i = 0; i < 256; ++i) s += w[i] * p[i];
    tt[tid] = s + ct1b[tid];
  }
  __syncthreads();
  if (tid == 0) {
    float mu = 0.f;
    for (int j = 0; j < 32; ++j) mu += tt[j];
    mu *= (1.f / 32.f);
    float va = 0.f;
    for (int j = 0; j < 32; ++j) { float d = tt[j] - mu; va += d * d; }
    va *= (1.f / 32.f);
    stats[0] = mu; stats[1] = rsqrtf(va + EPS_);
  }
  __syncthreads();
  if (tid < 32) {
    float v = (tt[tid] - stats[0]) * stats[1];
    tt[tid] = fmaxf(v * lng[tid] + lnb[tid], 0.f);
  }
  __syncthreads();
  float s = 0.f;
  const float* w2 = ct2w + tid * 32;
  #pragma unroll
  for (int j = 0; j < 32; ++j) s += w2[j] * tt[j];
  cw[b * 256 + tid] = s + ct2b[tid];
}

// --- per-batch proj weights ------------------------------------------------
__global__ void k_aproj(const float* __restrict__ projw, const float* __restrict__ cw,
                        unsigned short* __restrict__ aproj) {
  int gid = blockIdx.x * 256 + threadIdx.x;   // 16*65536
  int b = gid >> 16; int oi = gid & 65535; int i = oi & 255;
  aproj[gid] = f2bf(projw[oi] * cw[b * 256 + i]);
}

extern "C" void kernel_launch(void* const* d_in, const int* in_sizes, int n_in,
                              void* d_out, int out_size, void* d_ws, size_t ws_size,
                              hipStream_t stream) {
  (void)in_sizes; (void)n_in; (void)out_size; (void)ws_size;
  const float* x        = (const float*)d_in[0];
  const float* reduce_w = (const float*)d_in[1];
  const float* reduce_b = (const float*)d_in[2];
  const float* bn_g     = (const float*)d_in[3];
  const float* bn_b     = (const float*)d_in[4];
  const float* bn_mean  = (const float*)d_in[5];
  const float* bn_var   = (const float*)d_in[6];
  const float* conv_w   = (const float*)d_in[7];
  const float* conv1_w  = (const float*)d_in[8];
  const float* conv2_w  = (const float*)d_in[9];
  const float* conv3_w  = (const float*)d_in[10];
  const float* conv4_w  = (const float*)d_in[11];
  const float* chconv_w = (const float*)d_in[12];
  const float* cat_w    = (const float*)d_in[13];
  const float* ct1_w    = (const float*)d_in[14];
  const float* ct1_b    = (const float*)d_in[15];
  const float* ln_g     = (const float*)d_in[16];
  const float* ln_b     = (const float*)d_in[17];
  const float* ct2_w    = (const float*)d_in[18];
  const float* ct2_b    = (const float*)d_in[19];
  const float* proj_w   = (const float*)d_in[20];

  static bool attr_done = false;
  if (!attr_done) {
    hipFuncSetAttribute(reinterpret_cast<const void*>(&k_conv_gemm256),
                        hipFuncAttributeMaxDynamicSharedMemorySize, 131072);
    attr_done = true;
  }

  char* wsp = (char*)d_ws;
  size_t off = 0;
  auto alloc = [&](size_t bytes) -> char* {
    char* p = wsp + off; off += (bytes + 255) & ~(size_t)255; return p;
  };
  unsigned short* XH    = (unsigned short*)alloc((size_t)16 * 16384 * 256 * 2); // 134MB
  unsigned short* CAT   = (unsigned short*)alloc((size_t)16 * 4900 * 1280 * 2); // 201MB
  unsigned short* RBN   = (unsigned short*)alloc((size_t)16 * 16384 * 64 * 2);  // 33.5MB
  unsigned short* QKV   = (unsigned short*)alloc((size_t)16 * 4356 * 256 * 2);  // 35.7MB
  float*          CONT  = (float*)alloc((size_t)16 * 4096 * 4);
  float*          GPART = (float*)alloc((size_t)16 * 64 * 2304 * 4);            // 9.4MB
  float*          GRED  = (float*)alloc((size_t)16 * 2304 * 4);
  float*          POOL  = (float*)alloc(16 * 256 * 4);
  float*          CWB   = (float*)alloc(16 * 256 * 4);
  unsigned short* WR    = (unsigned short*)alloc((size_t)128 * 256 * 2);
  unsigned short* W2    = (unsigned short*)alloc((size_t)9 * 256 * 256 * 2);
  unsigned short* W3    = (unsigned short*)alloc((size_t)25 * 256 * 256 * 2);
  unsigned short* W4    = (unsigned short*)alloc((size_t)49 * 256 * 256 * 2);
  unsigned short* WBIG  = (unsigned short*)alloc((size_t)9 * 256 * 1280 * 2);
  unsigned short* APROJ = (unsigned short*)alloc((size_t)16 * 256 * 256 * 2);

  auto rp = [&](const float* s, unsigned short* d, int O, int Opad, int I, int T) {
    int tot = Opad * I * T;
    k_repack<<<(tot + 255) / 256, 256, 0, stream>>>(s, d, O, Opad, I, T);
  };
  rp(reduce_w, WR, 64, 128, 256, 1);
  rp(conv2_w, W2, 256, 256, 256, 9);
  rp(conv3_w, W3, 256, 256, 256, 25);
  rp(conv4_w, W4, 256, 256, 256, 49);
  k_fold1<<<9 * 256 * 5, 256, 0, stream>>>(cat_w, conv1_w, WBIG);

  k_border_zero<<<(16 * 804 * 160 + 255) / 256, 256, 0, stream>>>(CAT, 70, 3, 1280);
  k_border_zero<<<(16 * 260 * 32 + 255) / 256, 256, 0, stream>>>(QKV, 66, 1, 256);

  k_transpose_x<<<2048, 256, 0, stream>>>(x, XH);
  k_maxpool<<<8192, 256, 0, stream>>>(XH, CAT);

  dim3 blk(256);
  // reduce conv 1x1 (256->64 @128x128, Mpad=128) + BN + relu -> RBN
  k_conv_gemm<<<dim3(128, 1, 16), blk, 0, stream>>>(WR, XH, 64, 128, 256, 256, 0,
      128, 7, 128, 0, 1, 0, 0ULL, RBN, 64, 0, 128, 0, nullptr, 1,
      reduce_b, bn_g, bn_b, bn_mean, bn_var);
  k_haar<<<2048, 256, 0, stream>>>(RBN, CAT);
  // branch convs on qkv0 (CAT ch[0:256)) -> CAT slices (1280-ch layout)
  k_conv_gemm256<<<256, 1024, 131072, stream>>>(W2, CAT, 256, 1280, 0,
      70, 3, 3, 1, 0ULL, CAT, 1280, 256, 70, 3, nullptr, 0);
  k_conv_gemm256<<<256, 1024, 131072, stream>>>(W3, CAT, 256, 1280, 0,
      70, 3, 5, 2, 0ULL, CAT, 1280, 512, 70, 3, nullptr, 0);
  k_conv_gemm256<<<256, 1024, 131072, stream>>>(W4, CAT, 256, 1280, 0,
      70, 3, 7, 3, 0ULL, CAT, 1280, 768, 70, 3, nullptr, 0);
  // big conv (conv1 folded): 3x3 1280->256 over CAT -> QKV (padded 66x66)
  k_conv_gemm256<<<256, 1024, 131072, stream>>>(WBIG, CAT, 1280, 1280, 0,
      70, 3, 3, 1, 0ULL, QKV, 256, 0, 66, 1, nullptr, 0);
  k_content_logits<<<dim3(32, 16), blk, 0, stream>>>(QKV, conv_w, CONT);
  k_softmax4096<<<16, blk, 0, stream>>>(CONT);
  // pooled via G-correlation (parallel tail)
  k_corr<<<dim3(64, 16), blk, 0, stream>>>(QKV, CONT, GPART);
  k_gred<<<144, blk, 0, stream>>>(GPART, GRED);
  k_pooled_g<<<dim3(16, 16), blk, 0, stream>>>(GRED, chconv_w, POOL);
  k_ct<<<16, blk, 0, stream>>>(POOL, ct1_w, ct1_b, ln_g, ln_b, ct2_w, ct2_b, CWB);
  k_aproj<<<4096, 256, 0, stream>>>(proj_w, CWB, APROJ);
  // proj: per-batch A' = proj_w * cw, 1x1 over QKV -> d_out f32 NCHW
  k_conv_gemm256<<<256, 1024, 131072, stream>>>(APROJ, QKV, 256, 256, 0,
      66, 1, 1, 0, 65536ULL, nullptr, 256, 0, 64, 0, (float*)d_out, 2);
}

// Round 16
// 1359.454 us; speedup vs baseline: 1.0336x; 1.0336x over previous
//
#include <hip/hip_runtime.h>
#include <stdint.h>

// ---------------------------------------------------------------------------
// Dwtpool fused pipeline, MI355X gfx950.  FINAL (= r11/r14, measured 1362us):
//  - conv kernel: 256x256 tile, 8 waves, wave-tile 128x64, BK=32, 16x16x32
//    MFMA, 4 rotating 32KB LDS buffers, distance-2 gload_lds staging, counted
//    vmcnt(4), paired-row-line LDS rotation (0 conflicts), XCD swizzle.
//  - algebraic reductions: conv1 folded into big conv (Cin 1280);
//    channel-conv x softmax contracted to pooled = WC . G.
//  - parallel tail: k_corr 1024 blocks, k_gred, k_pooled_g 256 blocks.
// Session: 2606 -> 1362 us.  Schedule/occupancy matrix exhausted at ~47%
// MfmaUtil (LDS-BW + issue bound for this gather structure).
// ---------------------------------------------------------------------------

typedef __attribute__((ext_vector_type(8))) short bf16x8;
typedef __attribute__((ext_vector_type(4))) float f32x4;

#define EPS_ 1e-5f

#define GLOAD16(gp, lp)                                                        \
  __builtin_amdgcn_global_load_lds(                                            \
      (const __attribute__((address_space(1))) void*)(gp),                     \
      (__attribute__((address_space(3))) void*)(lp), 16, 0, 0)

__device__ __forceinline__ float bf2f(unsigned short u) {
  union { unsigned int u; float f; } c; c.u = ((unsigned int)u) << 16; return c.f;
}
__device__ __forceinline__ unsigned short f2bf(float f) {
  union { float f; unsigned int u; } c; c.f = f;
  return (unsigned short)((c.u + 0x7fffu + ((c.u >> 16) & 1u)) >> 16);
}
__device__ __forceinline__ void unpack8(uint4 v, float* f) {
  f[0]=bf2f((unsigned short)(v.x&0xffffu)); f[1]=bf2f((unsigned short)(v.x>>16));
  f[2]=bf2f((unsigned short)(v.y&0xffffu)); f[3]=bf2f((unsigned short)(v.y>>16));
  f[4]=bf2f((unsigned short)(v.z&0xffffu)); f[5]=bf2f((unsigned short)(v.z>>16));
  f[6]=bf2f((unsigned short)(v.w&0xffffu)); f[7]=bf2f((unsigned short)(v.w>>16));
}
__device__ __forceinline__ uint4 pack8(const float* f) {
  uint4 v;
  v.x = (unsigned)f2bf(f[0]) | ((unsigned)f2bf(f[1])<<16);
  v.y = (unsigned)f2bf(f[2]) | ((unsigned)f2bf(f[3])<<16);
  v.z = (unsigned)f2bf(f[4]) | ((unsigned)f2bf(f[5])<<16);
  v.w = (unsigned)f2bf(f[6]) | ((unsigned)f2bf(f[7])<<16);
  return v;
}

// --- weight repack: OIHW f32 -> [tap][Opad][I] bf16 (zero rows O..Opad) ----
__global__ void k_repack(const float* __restrict__ src, unsigned short* __restrict__ dst,
                         int O, int Opad, int I, int T) {
  int gid = blockIdx.x * 256 + threadIdx.x;
  if (gid >= Opad * I * T) return;
  int i = gid % I; int r = gid / I; int o = r % Opad; int t = r / Opad;
  dst[gid] = (o < O) ? f2bf(src[((size_t)(o * I + i)) * T + t]) : (unsigned short)0;
}

// --- fold conv1 into big-conv weights: WBIG[t][o][1280] bf16 ---------------
__global__ void k_fold1(const float* __restrict__ catw, const float* __restrict__ w1,
                        unsigned short* __restrict__ dst) {
  int gid = blockIdx.x; int tid = threadIdx.x;
  int iq = gid % 5; int o = (gid / 5) & 255; int t = gid / 1280;
  int i = iq * 256 + tid;
  float s;
  if (i < 256) {
    s = catw[((size_t)o * 1536 + i) * 9 + t];
    const float* cw = catw + ((size_t)o * 1536 + 256) * 9 + t;
    for (int m = 0; m < 256; ++m)
      s += cw[(size_t)m * 9] * w1[m * 256 + i];
  } else {
    s = catw[((size_t)o * 1536 + i + 256) * 9 + t];
  }
  dst[((size_t)t * 256 + o) * 1280 + i] = f2bf(s);
}

// --- zero border ring of a padded NHWC buffer (16 batches) -----------------
__global__ void k_border_zero(unsigned short* __restrict__ buf, int PW, int PB, int C) {
  int IW = PW - 2 * PB;
  int nb = PW * PW - IW * IW;
  int per = C >> 3;
  int gid = blockIdx.x * 256 + threadIdx.x;
  if (gid >= 16 * nb * per) return;
  int cq = gid % per; int r = gid / per; int p = r % nb; int b = r / nb;
  int y, x;
  int top = PB * PW;
  if (p < top) { y = p / PW; x = p - y * PW; }
  else if (p < top + IW * 2 * PB) {
    int q = p - top; y = PB + q / (2 * PB); int rr = q % (2 * PB);
    x = (rr < PB) ? rr : (IW + rr);
  } else { int q = p - top - IW * 2 * PB; y = PB + IW + q / PW; x = q - (q / PW) * PW; }
  uint4 z; z.x = z.y = z.z = z.w = 0u;
  *(uint4*)&buf[(((size_t)b * PW + y) * PW + x) * C + cq * 8] = z;
}

// --- x: NCHW f32 -> NHWC bf16 [16][128][128][256] --------------------------
__global__ void k_transpose_x(const float* __restrict__ x, unsigned short* __restrict__ xh) {
  int by = blockIdx.x; int b = by >> 7; int y = by & 127;
  int tid = threadIdx.x;
  __shared__ unsigned short lds[32 * 129];
  for (int c0 = 0; c0 < 256; c0 += 32) {
    #pragma unroll
    for (int i = 0; i < 16; ++i) {
      int e = i * 256 + tid; int ci = e >> 7, xx = e & 127;
      float v = x[(((size_t)b * 256 + c0 + ci) * 128 + y) * 128 + xx];
      lds[ci * 129 + xx] = f2bf(v);
    }
    __syncthreads();
    #pragma unroll
    for (int i2 = 0; i2 < 2; ++i2) {
      int e = i2 * 256 + tid; int pix = e >> 2, q = e & 3;
      unsigned int w0, w1, w2, w3;
      w0 = (unsigned)lds[(q*8+0)*129 + pix] | ((unsigned)lds[(q*8+1)*129 + pix] << 16);
      w1 = (unsigned)lds[(q*8+2)*129 + pix] | ((unsigned)lds[(q*8+3)*129 + pix] << 16);
      w2 = (unsigned)lds[(q*8+4)*129 + pix] | ((unsigned)lds[(q*8+5)*129 + pix] << 16);
      w3 = (unsigned)lds[(q*8+6)*129 + pix] | ((unsigned)lds[(q*8+7)*129 + pix] << 16);
      uint4 v; v.x = w0; v.y = w1; v.z = w2; v.w = w3;
      *(uint4*)&xh[(((size_t)b * 128 + y) * 128 + pix) * 256 + c0 + q * 8] = v;
    }
    __syncthreads();
  }
}

// --- maxpool 2x2 on xh -> CAT(padded 70x70, 1280ch) channels [1024..1280) --
__global__ void k_maxpool(const unsigned short* __restrict__ xh, unsigned short* __restrict__ cat) {
  int gid = blockIdx.x * 256 + threadIdx.x;        // 16*4096*32
  int cq = gid & 31; int pix = gid >> 5;
  int bb = pix >> 12; int yx = pix & 4095;
  int y = yx >> 6, xx2 = yx & 63;
  size_t base = (((size_t)bb * 128 + 2 * y) * 128 + 2 * xx2) * 256 + cq * 8;
  uint4 v00 = *(const uint4*)(xh + base);
  uint4 v01 = *(const uint4*)(xh + base + 256);
  uint4 v10 = *(const uint4*)(xh + base + 32768);
  uint4 v11 = *(const uint4*)(xh + base + 32768 + 256);
  float a[8], b8[8], c8[8], d8[8], m8[8];
  unpack8(v00, a); unpack8(v01, b8); unpack8(v10, c8); unpack8(v11, d8);
  #pragma unroll
  for (int j = 0; j < 8; ++j) m8[j] = fmaxf(fmaxf(a[j], b8[j]), fmaxf(c8[j], d8[j]));
  *(uint4*)(cat + (((size_t)bb * 4900 + (y + 3) * 70 + (xx2 + 3))) * 1280 + 1024 + cq * 8) = pack8(m8);
}

// --- haar DWT: rbn [16][128][128][64] -> CAT(padded,1280) ch [0..256) ------
__global__ void k_haar(const unsigned short* __restrict__ rbn, unsigned short* __restrict__ cat) {
  int gid = blockIdx.x * 256 + threadIdx.x;        // 16*4096*8
  int cq = gid & 7; int pix = gid >> 3;
  int bb = pix >> 12; int yx = pix & 4095;
  int y = yx >> 6, xx = yx & 63;
  size_t base = (((size_t)bb * 128 + 2 * y) * 128 + 2 * xx) * 64 + cq * 8;
  uint4 va = *(const uint4*)(rbn + base);
  uint4 vb = *(const uint4*)(rbn + base + 64);
  uint4 vc = *(const uint4*)(rbn + base + 8192);
  uint4 vd = *(const uint4*)(rbn + base + 8192 + 64);
  float a[8], b8[8], c8[8], d8[8], o[8];
  unpack8(va, a); unpack8(vb, b8); unpack8(vc, c8); unpack8(vd, d8);
  size_t ob = ((size_t)bb * 4900 + (y + 3) * 70 + (xx + 3)) * 1280 + cq * 8;
  #pragma unroll
  for (int j = 0; j < 8; ++j) o[j] = (a[j] + b8[j] + c8[j] + d8[j]) * 0.5f;
  *(uint4*)(cat + ob + 0)   = pack8(o);
  #pragma unroll
  for (int j = 0; j < 8; ++j) o[j] = (a[j] + b8[j] - c8[j] - d8[j]) * 0.5f;
  *(uint4*)(cat + ob + 64)  = pack8(o);
  #pragma unroll
  for (int j = 0; j < 8; ++j) o[j] = (a[j] - b8[j] + c8[j] - d8[j]) * 0.5f;
  *(uint4*)(cat + ob + 128) = pack8(o);
  #pragma unroll
  for (int j = 0; j < 8; ++j) o[j] = (a[j] - b8[j] - c8[j] + d8[j]) * 0.5f;
  *(uint4*)(cat + ob + 192) = pack8(o);
}

// ===========================================================================
// 256x256 implicit-GEMM conv (r5-verified): 8 waves, wave-tile 128x64, BK=32,
// 4 rotating 32KB LDS buffers, distance-2 staging, counted vmcnt(4).
// ===========================================================================
__global__ __launch_bounds__(512, 1) void k_conv_gemm256(
    const unsigned short* __restrict__ Wt, const unsigned short* __restrict__ Bf,
    int Cin, int Cstr, int cbase,
    int PW, int PB, int KH, int pad,
    unsigned long long wbstride,
    unsigned short* __restrict__ outb, int OCstr, int ocbase, int OPW, int OPB,
    float* __restrict__ outf, int mode) {
  const int tid = threadIdx.x, lane = tid & 63, w = tid >> 6;
  const int wm = w >> 2, wn = w & 3;
  const int nidx = (blockIdx.x & 7) * 32 + (blockIdx.x >> 3);
  const int bn = (nidx & 15) * 256;
  const int b = nidx >> 4;
  if (wbstride) Wt += (size_t)b * wbstride;
  extern __shared__ unsigned short S[];   // 4 buffers x 16384 shorts = 128KB

  f32x4 zero4 = {0.f, 0.f, 0.f, 0.f};
  f32x4 acc[8][4];
  #pragma unroll
  for (int i = 0; i < 8; ++i)
    #pragma unroll
    for (int j = 0; j < 4; ++j) acc[i][j] = zero4;

  const int lq = lane >> 3, lc = lane & 7;
  const int lg = (lc - lq) & 7;
  const int pr = lg >> 2;
  const int ks = lg & 3;
  const unsigned short* aSt = Wt + (size_t)(w * 32 + 2 * lq + pr) * Cin + ks * 8;
  const size_t jA = (size_t)16 * Cin;
  const size_t bimg = (size_t)b * PW * PW;
  const unsigned short* bSt0; const unsigned short* bSt1;
  {
    int p = bn + w * 32 + 2 * lq + pr;
    bSt0 = Bf + (bimg + (size_t)((p >> 6) + PB) * PW + ((p & 63) + PB)) * Cstr + cbase + ks * 8;
    p += 16;
    bSt1 = Bf + (bimg + (size_t)((p >> 6) + PB) * PW + ((p & 63) + PB)) * Cstr + cbase + ks * 8;
  }
  const int dA = w * 1024;
  const int dB = 8192 + w * 1024;

  const int r = lane & 15, s4 = lane >> 4;
  const int ck = (((r & 1) * 4 + s4) + ((r >> 1) & 7)) & 7;
  const int lb = (r >> 1) * 64 + ck * 8;
  const int aOff = wm * 4096 + lb;
  const int bOff = 8192 + wn * 2048 + lb;

  const size_t MC = (size_t)256 * Cin;
  const int NT = (KH * KH * Cin) >> 5;

  const long long t0B = ((long long)(-pad) * PW + (-pad)) * (long long)Cstr;
  GLOAD16(aSt,             S + dA);
  GLOAD16(aSt + jA,        S + dA + 512);
  GLOAD16(bSt0 + t0B,      S + dB);
  GLOAD16(bSt1 + t0B,      S + dB + 512);
  GLOAD16(aSt + 32,        S + 16384 + dA);
  GLOAD16(aSt + jA + 32,   S + 16384 + dA + 512);
  GLOAD16(bSt0 + t0B + 32, S + 16384 + dB);
  GLOAD16(bSt1 + t0B + 32, S + 16384 + dB + 512);
  asm volatile("s_waitcnt vmcnt(4)" ::: "memory");
  __builtin_amdgcn_s_barrier();
  __builtin_amdgcn_sched_barrier(0);

  int kc2 = 64, ty2 = 0, tx2 = 0;
  for (int t = 0; t < NT; ++t) {
    const unsigned short* Sc = S + (t & 3) * 16384;
    unsigned short* Sn = (unsigned short*)S + ((t + 2) & 3) * 16384;
    const bool hn = (t + 2) < NT;
    long long offA = 0, offB = 0;
    if (hn) {
      offA = (long long)(ty2 * KH + tx2) * MC + kc2;
      offB = ((long long)(ty2 - pad) * PW + (tx2 - pad)) * (long long)Cstr + kc2;
      kc2 += 32;
      if (kc2 == Cin) { kc2 = 0; ++tx2; if (tx2 == KH) { tx2 = 0; ++ty2; } }
    }
    bf16x8 a[4], bb[4];
    // ---- phase 0: frags A(mi0-3)+B; stage A of tile t+2 ----
    #pragma unroll
    for (int mi = 0; mi < 4; ++mi) a[mi] = *(const bf16x8*)(Sc + aOff + mi * 512);
    #pragma unroll
    for (int ni = 0; ni < 4; ++ni) bb[ni] = *(const bf16x8*)(Sc + bOff + ni * 512);
    if (hn) {
      GLOAD16(aSt + offA,      Sn + dA);
      GLOAD16(aSt + jA + offA, Sn + dA + 512);
    }
    __builtin_amdgcn_s_setprio(1);
    #pragma unroll
    for (int mi = 0; mi < 4; ++mi)
      #pragma unroll
      for (int ni = 0; ni < 4; ++ni)
        acc[mi][ni] = __builtin_amdgcn_mfma_f32_16x16x32_bf16(a[mi], bb[ni], acc[mi][ni], 0, 0, 0);
    __builtin_amdgcn_s_setprio(0);
    __builtin_amdgcn_s_barrier();
    // ---- phase 1: frags A(mi4-7); stage B of tile t+2 ----
    #pragma unroll
    for (int mi = 0; mi < 4; ++mi) a[mi] = *(const bf16x8*)(Sc + aOff + (mi + 4) * 512);
    if (hn) {
      GLOAD16(bSt0 + offB, Sn + dB);
      GLOAD16(bSt1 + offB, Sn + dB + 512);
    }
    __builtin_amdgcn_s_setprio(1);
    #pragma unroll
    for (int mi = 0; mi < 4; ++mi)
      #pragma unroll
      for (int ni = 0; ni < 4; ++ni)
        acc[mi + 4][ni] = __builtin_amdgcn_mfma_f32_16x16x32_bf16(a[mi], bb[ni], acc[mi + 4][ni], 0, 0, 0);
    __builtin_amdgcn_s_setprio(0);
    // ---- tile boundary: counted wait + barrier ----
    if (t + 1 < NT) {
      if (t + 2 < NT) { asm volatile("s_waitcnt vmcnt(4)" ::: "memory"); }
      else            { asm volatile("s_waitcnt vmcnt(0)" ::: "memory"); }
      __builtin_amdgcn_s_barrier();
      __builtin_amdgcn_sched_barrier(0);
    }
  }

  const size_t bimgO = (size_t)b * OPW * OPW;
  #pragma unroll
  for (int mi = 0; mi < 8; ++mi) {
    const int mf = wm * 128 + mi * 16 + (lane >> 4) * 4;
    #pragma unroll
    for (int ni = 0; ni < 4; ++ni) {
      const int n = bn + wn * 64 + ni * 16 + (lane & 15);
      if (mode == 2) {
        #pragma unroll
        for (int vv = 0; vv < 4; ++vv)
          outf[((size_t)b * 256 + mf + vv) * 4096 + n] = acc[mi][ni][vv];
      } else {
        const int oy = n >> 6, ox = n & 63;
        unsigned short h[4];
        #pragma unroll
        for (int vv = 0; vv < 4; ++vv) h[vv] = f2bf(acc[mi][ni][vv]);
        uint2 st; st.x = (unsigned)h[0] | ((unsigned)h[1] << 16);
        st.y = (unsigned)h[2] | ((unsigned)h[3] << 16);
        *(uint2*)&outb[(bimgO + (size_t)(oy + OPB) * OPW + (ox + OPB)) * OCstr + ocbase + mf] = st;
      }
    }
  }
}

// --- 128^2 implicit-GEMM conv (kept for M=64 reduce conv, mode 1) ----------
__global__ __launch_bounds__(256) void k_conv_gemm(
    const unsigned short* __restrict__ Wt, const unsigned short* __restrict__ Bf,
    int M, int Mpad, int Cin, int Cstr, int cbase,
    int OW, int lgOW, int PW, int PB, int KH, int pad,
    unsigned long long wbstride,
    unsigned short* __restrict__ outb, int OCstr, int ocbase, int OPW, int OPB,
    float* __restrict__ outf, int mode,
    const float* __restrict__ rb, const float* __restrict__ bng, const float* __restrict__ bnb,
    const float* __restrict__ bnm, const float* __restrict__ bnv) {
  const int tid = threadIdx.x, lane = tid & 63, w = tid >> 6;
  const int wm = w >> 1, wn = w & 1;
  const int bm = blockIdx.y * 128, bn = blockIdx.x * 128;
  const int b = blockIdx.z;
  const int Npix = OW * OW;
  if (wbstride) Wt += (size_t)b * wbstride;

  __shared__ __align__(1024) unsigned short sA[128 * 32];
  __shared__ __align__(1024) unsigned short sB[128 * 32];

  f32x4 zero4 = {0.f, 0.f, 0.f, 0.f};
  f32x4 acc[4][4];
  #pragma unroll
  for (int i = 0; i < 4; ++i)
    #pragma unroll
    for (int j = 0; j < 4; ++j) acc[i][j] = zero4;

  const int srow = lane >> 2;
  const int slog = (lane & 3) ^ ((lane >> 3) & 3);
  const int r0 = w * 32;
  const unsigned short* aRow = Wt + ((size_t)(bm + r0 + srow)) * Cin + slog * 8;
  const int n0 = bn + r0 + srow, n1 = n0 + 16;
  const int y0 = n0 >> lgOW, x0 = n0 & (OW - 1);
  const int y1 = n1 >> lgOW, x1 = n1 & (OW - 1);
  const size_t bimg = (size_t)b * PW * PW;
  const unsigned short* bRow0 = Bf + (bimg + (size_t)(y0 + PB) * PW + (x0 + PB)) * Cstr + cbase + slog * 8;
  const unsigned short* bRow1 = Bf + (bimg + (size_t)(y1 + PB) * PW + (x1 + PB)) * Cstr + cbase + slog * 8;
  unsigned short* ldsA0 = &sA[(r0) * 32];
  unsigned short* ldsA1 = &sA[(r0 + 16) * 32];
  unsigned short* ldsB0 = &sB[(r0) * 32];
  unsigned short* ldsB1 = &sB[(r0 + 16) * 32];

  const int rowfrag = lane & 15, hi = lane >> 4;
  const int sl = hi ^ ((rowfrag >> 1) & 3);
  const bf16x8* pA[4]; const bf16x8* pB[4];
  #pragma unroll
  for (int mi = 0; mi < 4; ++mi)
    pA[mi] = (const bf16x8*)&sA[(wm * 64 + mi * 16 + rowfrag) * 32 + sl * 8];
  #pragma unroll
  for (int ni = 0; ni < 4; ++ni)
    pB[ni] = (const bf16x8*)&sB[(wn * 64 + ni * 16 + rowfrag) * 32 + sl * 8];

  const size_t MC = (size_t)Mpad * Cin;
  for (int ty = 0; ty < KH; ++ty) {
    for (int tx = 0; tx < KH; ++tx) {
      const unsigned short* at = aRow + (size_t)(ty * KH + tx) * MC;
      const long long toff = ((long long)(ty - pad) * PW + (tx - pad)) * Cstr;
      const unsigned short* bt0 = bRow0 + toff;
      const unsigned short* bt1 = bRow1 + toff;
      for (int kc = 0; kc < Cin; kc += 32) {
        GLOAD16(at + kc, ldsA0);
        GLOAD16(at + (size_t)16 * Cin + kc, ldsA1);
        GLOAD16(bt0 + kc, ldsB0);
        GLOAD16(bt1 + kc, ldsB1);
        __syncthreads();
        bf16x8 af[4], bfr[4];
        #pragma unroll
        for (int mi = 0; mi < 4; ++mi) af[mi] = *pA[mi];
        #pragma unroll
        for (int ni = 0; ni < 4; ++ni) bfr[ni] = *pB[ni];
        #pragma unroll
        for (int mi = 0; mi < 4; ++mi)
          #pragma unroll
          for (int ni = 0; ni < 4; ++ni)
            acc[mi][ni] = __builtin_amdgcn_mfma_f32_16x16x32_bf16(af[mi], bfr[ni], acc[mi][ni], 0, 0, 0);
        __syncthreads();
      }
    }
  }

  const int mb0 = bm + wm * 64, nb0 = bn + wn * 64;
  const size_t bimgO = (size_t)b * OPW * OPW;
  #pragma unroll
  for (int mi = 0; mi < 4; ++mi) {
    const int mf = mb0 + mi * 16 + (lane >> 4) * 4;
    if (mf >= M) continue;
    #pragma unroll
    for (int ni = 0; ni < 4; ++ni) {
      const int n = nb0 + ni * 16 + (lane & 15);
      if (mode == 2) {
        #pragma unroll
        for (int vv = 0; vv < 4; ++vv)
          outf[((size_t)b * M + mf + vv) * Npix + n] = acc[mi][ni][vv];
      } else {
        const int oy = n >> lgOW, ox = n & (OW - 1);
        unsigned short h[4];
        #pragma unroll
        for (int vv = 0; vv < 4; ++vv) {
          float val = acc[mi][ni][vv];
          if (mode == 1) {
            int m = mf + vv;
            float scl = bng[m] * rsqrtf(bnv[m] + EPS_);
            val = (val + rb[m] - bnm[m]) * scl + bnb[m];
            val = fmaxf(val, 0.f);
          }
          h[vv] = f2bf(val);
        }
        uint2 st; st.x = (unsigned)h[0] | ((unsigned)h[1] << 16);
        st.y = (unsigned)h[2] | ((unsigned)h[3] << 16);
        *(uint2*)&outb[(bimgO + (size_t)(oy + OPB) * OPW + (ox + OPB)) * OCstr + ocbase + mf] = st;
      }
    }
  }
}

// --- content logits: dot(qkv[pix], w) over 256 ch --------------------------
__global__ void k_content_logits(const unsigned short* __restrict__ qkv,
                                 const float* __restrict__ conv_w,
                                 float* __restrict__ logits) {
  int j = blockIdx.x, b = blockIdx.y, tid = threadIdx.x;
  __shared__ float wl[256];
  wl[tid] = conv_w[tid];
  __syncthreads();
  int pl = tid >> 3, kp = tid & 7;
  #pragma unroll
  for (int pass = 0; pass < 4; ++pass) {
    int p = j * 128 + pass * 32 + pl;
    int y = p >> 6, x = p & 63;
    const unsigned short* q = qkv + (((size_t)b * 66 + y + 1) * 66 + (x + 1)) * 256 + kp * 32;
    float s = 0.f;
    #pragma unroll
    for (int i = 0; i < 32; i += 8) {
      uint4 v = *(const uint4*)(q + i);
      float f[8]; unpack8(v, f);
      #pragma unroll
      for (int k = 0; k < 8; ++k) s += f[k] * wl[kp * 32 + i + k];
    }
    s += __shfl_down(s, 4, 8);
    s += __shfl_down(s, 2, 8);
    s += __shfl_down(s, 1, 8);
    if (kp == 0) logits[(size_t)b * 4096 + p] = s;
  }
}

// --- softmax over 4096 per batch (in place) --------------------------------
__global__ void k_softmax4096(float* __restrict__ cont) {
  int b = blockIdx.x, tid = threadIdx.x;
  __shared__ float red[256];
  float sv[16]; float mx = -1e30f;
  #pragma unroll
  for (int j = 0; j < 16; ++j) { sv[j] = cont[(size_t)b * 4096 + j * 256 + tid]; mx = fmaxf(mx, sv[j]); }
  red[tid] = mx; __syncthreads();
  for (int s = 128; s > 0; s >>= 1) { if (tid < s) red[tid] = fmaxf(red[tid], red[tid + s]); __syncthreads(); }
  mx = red[0]; __syncthreads();
  float sum = 0.f;
  #pragma unroll
  for (int j = 0; j < 16; ++j) { sv[j] = expf(sv[j] - mx); sum += sv[j]; }
  red[tid] = sum; __syncthreads();
  for (int s = 128; s > 0; s >>= 1) { if (tid < s) red[tid] += red[tid + s]; __syncthreads(); }
  float inv = 1.f / red[0];
  #pragma unroll
  for (int j = 0; j < 16; ++j) cont[(size_t)b * 4096 + j * 256 + tid] = sv[j] * inv;
}

// --- G correlation, per-row: gpart[b][j][t][i], j = qkv row 0..63 ----------
__global__ void k_corr(const unsigned short* __restrict__ qkv,
                       const float* __restrict__ cont, float* __restrict__ gpart) {
  int j = blockIdx.x, b = blockIdx.y, i = threadIdx.x;   // j: row 0..63
  __shared__ float cl[192];                              // content rows j-1,j,j+1
  if (i < 192) {
    int gy = j - 1 + (i >> 6);
    cl[i] = (gy >= 0 && gy < 64) ? cont[(size_t)b * 4096 + gy * 64 + (i & 63)] : 0.f;
  }
  __syncthreads();
  float g[9] = {0.f, 0.f, 0.f, 0.f, 0.f, 0.f, 0.f, 0.f, 0.f};
  const unsigned short* qrow = qkv + (((size_t)b * 66 + j + 1) * 66 + 1) * 256 + i;
  for (int x = 0; x < 64; ++x) {
    float qv = bf2f(qrow[(size_t)x * 256]);
    #pragma unroll
    for (int ky = 0; ky < 3; ++ky) {
      const int ly = 2 - ky;                             // content row j-ky+1
      #pragma unroll
      for (int kx = 0; kx < 3; ++kx) {
        int nx = x - kx + 1;
        if ((unsigned)nx < 64u) g[ky * 3 + kx] += qv * cl[ly * 64 + nx];
      }
    }
  }
  size_t base = ((size_t)b * 64 + j) * 2304 + i;
  #pragma unroll
  for (int t = 0; t < 9; ++t) gpart[base + t * 256] = g[t];
}

// --- reduce gpart over 64 rows: gred[b][t*256+i] ---------------------------
__global__ void k_gred(const float* __restrict__ gpart, float* __restrict__ gred) {
  int gid = blockIdx.x * 256 + threadIdx.x;              // 16*2304
  if (gid >= 16 * 2304) return;
  int b = gid / 2304, e = gid - b * 2304;
  float s = 0.f;
  const float* p = gpart + (size_t)b * 64 * 2304 + e;
  for (int j = 0; j < 64; ++j) s += p[(size_t)j * 2304];
  gred[gid] = s;
}

// --- pooled[b][c] = sum_{i,t} wc[c][i][t] * G[t][i]  (256 blocks) ----------
__global__ void k_pooled_g(const float* __restrict__ gred,
                           const float* __restrict__ wc, float* __restrict__ pooled) {
  int cg = blockIdx.x, b = blockIdx.y;                   // cg 0..15
  int tid = threadIdx.x;
  int cl_ = tid >> 4, part = tid & 15;                   // 16 ch x 16 parts
  __shared__ float Gs[2304];
  __shared__ float red[256];
  for (int e = tid; e < 2304; e += 256) {
    int i = e / 9, t = e - i * 9;
    Gs[e] = gred[(size_t)b * 2304 + t * 256 + i];        // Gs[i*9+t] = G[t][i]
  }
  __syncthreads();
  int c = cg * 16 + cl_;
  const float* w = wc + (size_t)c * 2304 + part;
  float acc = 0.f;
  #pragma unroll 4
  for (int q = 0; q < 144; ++q) acc += w[q * 16] * Gs[part + q * 16];
  red[tid] = acc;
  __syncthreads();
  if (part == 0) {
    float s = 0.f;
    #pragma unroll
    for (int q = 0; q < 16; ++q) s += red[cl_ * 16 + q];
    pooled[b * 256 + c] = s;
  }
}

// --- ct1 -> LN -> relu -> ct2 ----------------------------------------------
__global__ void k_ct(const float* __restrict__ pooled,
                     const float* __restrict__ ct1w, const float* __restrict__ ct1b,
                     const float* __restrict__ lng, const float* __restrict__ lnb,
                     const float* __restrict__ ct2w, const float* __restrict__ ct2b,
                     float* __restrict__ cw) {
  int b = blockIdx.x, tid = threadIdx.x;
  __shared__ float tt[32];
  __shared__ float stats[2];
  if (tid < 32) {
    float s = 0.f;
    const float* w = ct1w + tid * 256;
    const float* p = pooled + b * 256;
    for (int i = 0; i < 256; ++i) s += w[i] * p[i];
    tt[tid] = s + ct1b[tid];
  }
  __syncthreads();
  if (tid == 0) {
    float mu = 0.f;
    for (int j = 0; j < 32; ++j) mu += tt[j];
    mu *= (1.f / 32.f);
    float va = 0.f;
    for (int j = 0; j < 32; ++j) { float d = tt[j] - mu; va += d * d; }
    va *= (1.f / 32.f);
    stats[0] = mu; stats[1] = rsqrtf(va + EPS_);
  }
  __syncthreads();
  if (tid < 32) {
    float v = (tt[tid] - stats[0]) * stats[1];
    tt[tid] = fmaxf(v * lng[tid] + lnb[tid], 0.f);
  }
  __syncthreads();
  float s = 0.f;
  const float* w2 = ct2w + tid * 32;
  #pragma unroll
  for (int j = 0; j < 32; ++j) s += w2[j] * tt[j];
  cw[b * 256 + tid] = s + ct2b[tid];
}

// --- per-batch proj weights ------------------------------------------------
__global__ void k_aproj(const float* __restrict__ projw, const float* __restrict__ cw,
                        unsigned short* __restrict__ aproj) {
  int gid = blockIdx.x * 256 + threadIdx.x;   // 16*65536
  int b = gid >> 16; int oi = gid & 65535; int i = oi & 255;
  aproj[gid] = f2bf(projw[oi] * cw[b * 256 + i]);
}

extern "C" void kernel_launch(void* const* d_in, const int* in_sizes, int n_in,
                              void* d_out, int out_size, void* d_ws, size_t ws_size,
                              hipStream_t stream) {
  (void)in_sizes; (void)n_in; (void)out_size; (void)ws_size;
  const float* x        = (const float*)d_in[0];
  const float* reduce_w = (const float*)d_in[1];
  const float* reduce_b = (const float*)d_in[2];
  const float* bn_g     = (const float*)d_in[3];
  const float* bn_b     = (const float*)d_in[4];
  const float* bn_mean  = (const float*)d_in[5];
  const float* bn_var   = (const float*)d_in[6];
  const float* conv_w   = (const float*)d_in[7];
  const float* conv1_w  = (const float*)d_in[8];
  const float* conv2_w  = (const float*)d_in[9];
  const float* conv3_w  = (const float*)d_in[10];
  const float* conv4_w  = (const float*)d_in[11];
  const float* chconv_w = (const float*)d_in[12];
  const float* cat_w    = (const float*)d_in[13];
  const float* ct1_w    = (const float*)d_in[14];
  const float* ct1_b    = (const float*)d_in[15];
  const float* ln_g     = (const float*)d_in[16];
  const float* ln_b     = (const float*)d_in[17];
  const float* ct2_w    = (const float*)d_in[18];
  const float* ct2_b    = (const float*)d_in[19];
  const float* proj_w   = (const float*)d_in[20];

  static bool attr_done = false;
  if (!attr_done) {
    hipFuncSetAttribute(reinterpret_cast<const void*>(&k_conv_gemm256),
                        hipFuncAttributeMaxDynamicSharedMemorySize, 131072);
    attr_done = true;
  }

  char* wsp = (char*)d_ws;
  size_t off = 0;
  auto alloc = [&](size_t bytes) -> char* {
    char* p = wsp + off; off += (bytes + 255) & ~(size_t)255; return p;
  };
  unsigned short* XH    = (unsigned short*)alloc((size_t)16 * 16384 * 256 * 2); // 134MB
  unsigned short* CAT   = (unsigned short*)alloc((size_t)16 * 4900 * 1280 * 2); // 201MB
  unsigned short* RBN   = (unsigned short*)alloc((size_t)16 * 16384 * 64 * 2);  // 33.5MB
  unsigned short* QKV   = (unsigned short*)alloc((size_t)16 * 4356 * 256 * 2);  // 35.7MB
  float*          CONT  = (float*)alloc((size_t)16 * 4096 * 4);
  float*          GPART = (float*)alloc((size_t)16 * 64 * 2304 * 4);            // 9.4MB
  float*          GRED  = (float*)alloc((size_t)16 * 2304 * 4);
  float*          POOL  = (float*)alloc(16 * 256 * 4);
  float*          CWB   = (float*)alloc(16 * 256 * 4);
  unsigned short* WR    = (unsigned short*)alloc((size_t)128 * 256 * 2);
  unsigned short* W2    = (unsigned short*)alloc((size_t)9 * 256 * 256 * 2);
  unsigned short* W3    = (unsigned short*)alloc((size_t)25 * 256 * 256 * 2);
  unsigned short* W4    = (unsigned short*)alloc((size_t)49 * 256 * 256 * 2);
  unsigned short* WBIG  = (unsigned short*)alloc((size_t)9 * 256 * 1280 * 2);
  unsigned short* APROJ = (unsigned short*)alloc((size_t)16 * 256 * 256 * 2);

  auto rp = [&](const float* s, unsigned short* d, int O, int Opad, int I, int T) {
    int tot = Opad * I * T;
    k_repack<<<(tot + 255) / 256, 256, 0, stream>>>(s, d, O, Opad, I, T);
  };
  rp(reduce_w, WR, 64, 128, 256, 1);
  rp(conv2_w, W2, 256, 256, 256, 9);
  rp(conv3_w, W3, 256, 256, 256, 25);
  rp(conv4_w, W4, 256, 256, 256, 49);
  k_fold1<<<9 * 256 * 5, 256, 0, stream>>>(cat_w, conv1_w, WBIG);

  k_border_zero<<<(16 * 804 * 160 + 255) / 256, 256, 0, stream>>>(CAT, 70, 3, 1280);
  k_border_zero<<<(16 * 260 * 32 + 255) / 256, 256, 0, stream>>>(QKV, 66, 1, 256);

  k_transpose_x<<<2048, 256, 0, stream>>>(x, XH);
  k_maxpool<<<8192, 256, 0, stream>>>(XH, CAT);

  dim3 blk(256);
  // reduce conv 1x1 (256->64 @128x128, Mpad=128) + BN + relu -> RBN
  k_conv_gemm<<<dim3(128, 1, 16), blk, 0, stream>>>(WR, XH, 64, 128, 256, 256, 0,
      128, 7, 128, 0, 1, 0, 0ULL, RBN, 64, 0, 128, 0, nullptr, 1,
      reduce_b, bn_g, bn_b, bn_mean, bn_var);
  k_haar<<<2048, 256, 0, stream>>>(RBN, CAT);
  // branch convs on qkv0 (CAT ch[0:256)) -> CAT slices (1280-ch layout)
  k_conv_gemm256<<<256, 512, 131072, stream>>>(W2, CAT, 256, 1280, 0,
      70, 3, 3, 1, 0ULL, CAT, 1280, 256, 70, 3, nullptr, 0);
  k_conv_gemm256<<<256, 512, 131072, stream>>>(W3, CAT, 256, 1280, 0,
      70, 3, 5, 2, 0ULL, CAT, 1280, 512, 70, 3, nullptr, 0);
  k_conv_gemm256<<<256, 512, 131072, stream>>>(W4, CAT, 256, 1280, 0,
      70, 3, 7, 3, 0ULL, CAT, 1280, 768, 70, 3, nullptr, 0);
  // big conv (conv1 folded): 3x3 1280->256 over CAT -> QKV (padded 66x66)
  k_conv_gemm256<<<256, 512, 131072, stream>>>(WBIG, CAT, 1280, 1280, 0,
      70, 3, 3, 1, 0ULL, QKV, 256, 0, 66, 1, nullptr, 0);
  k_content_logits<<<dim3(32, 16), blk, 0, stream>>>(QKV, conv_w, CONT);
  k_softmax4096<<<16, blk, 0, stream>>>(CONT);
  // pooled via G-correlation (parallel tail)
  k_corr<<<dim3(64, 16), blk, 0, stream>>>(QKV, CONT, GPART);
  k_gred<<<144, blk, 0, stream>>>(GPART, GRED);
  k_pooled_g<<<dim3(16, 16), blk, 0, stream>>>(GRED, chconv_w, POOL);
  k_ct<<<16, blk, 0, stream>>>(POOL, ct1_w, ct1_b, ln_g, ln_b, ct2_w, ct2_b, CWB);
  k_aproj<<<4096, 256, 0, stream>>>(proj_w, CWB, APROJ);
  // proj: per-batch A' = proj_w * cw, 1x1 over QKV -> d_out f32 NCHW
  k_conv_gemm256<<<256, 512, 131072, stream>>>(APROJ, QKV, 256, 256, 0,
      66, 1, 1, 0, 65536ULL, nullptr, 256, 0, 64, 0, (float*)d_out, 2);
}